// Round 3
// baseline (1452.050 us; speedup 1.0000x reference)
//
#include <hip/hip_runtime.h>
#include <cstdint>
#include <cstddef>

#define HW 4096
#define CDIM 768
#define PPIX 4356   // 66*66 padded pixels

typedef unsigned short u16;
typedef __attribute__((ext_vector_type(8))) short short8;
typedef __attribute__((ext_vector_type(4))) float f32x4;

__device__ __forceinline__ float bf2f(u16 u) { return __uint_as_float(((unsigned)u) << 16); }
__device__ __forceinline__ u16 f2bf(float f) {
    unsigned u = __float_as_uint(f);
    unsigned r = (u + 0x7fffu + ((u >> 16) & 1u)) >> 16;
    return (u16)r;
}
__device__ __forceinline__ float lof(unsigned u) { return __uint_as_float(u << 16); }
__device__ __forceinline__ float hif(unsigned u) { return __uint_as_float(u & 0xffff0000u); }
__device__ __forceinline__ unsigned pkbf(float lo, float hi) {
    return (unsigned)f2bf(lo) | ((unsigned)f2bf(hi) << 16);
}
__device__ __forceinline__ int swz(int r) { return ((r >> 1) ^ (r >> 3)) & 3; }

__device__ __forceinline__ void gl16(const u16* g, u16* l) {
    __builtin_amdgcn_global_load_lds(
        (const __attribute__((address_space(1))) unsigned int*)g,
        (__attribute__((address_space(3))) unsigned int*)l, 16, 0, 0);
}

// ---------------------------------------------------------------- GEMM core
// C[4096, N] = A[4096, K] @ B^T, B row-major [N][768-per-sub] bf16.
// Tile 128x256, BK=32, 4 waves (2x2), wave tile 64x128 (4x8 frags of 16x16x32).
// Double-buffered LDS, single barrier per K-step. LDS layout = gl16 linear
// order == [row][4 chunks of 16B] with chunk position (t&3), holding source
// chunk (t&3)^swz(row). Frag read: chunk quad^swz(row) -> 2-way only (free).
enum GMode { G_CONV = 0, G_DEFORM = 1, G_PROJ = 2, G_SPAT = 3 };

struct ProjP {
    const u16* b1[5];
    const u16* b2[5];
    int ch[5];
    int choff[5];
};

template <int MODE>
__launch_bounds__(256, 2)
__global__ void k_gemm(const u16* __restrict__ xpad,  // [5][4356][768] bf16 padded image
                       const u16* __restrict__ blkA,  // proj A1 (blk) / spat A (xatt)
                       const u16* __restrict__ Wt,    // conv/deform B [9][768][768] / spat B
                       const int4* __restrict__ idx4, // [5][9][4096] padded row offsets (pre *768)
                       const float4* __restrict__ w4, // [5][9][4096] fused weights
                       const float* __restrict__ bias,
                       u16* __restrict__ outb,        // bf16 out (om / dout)
                       float* __restrict__ outf,      // fp32 out (Xcat / P2)
                       ProjP pp) {
    const int z = blockIdx.z;
    const int m0 = blockIdx.x * 128;
    const int n0 = blockIdx.y * 256;

    int Nrows, ntap, choff = 0, ldo = CDIM;
    const u16 *Az = nullptr, *Ac = nullptr, *B1 = nullptr, *B2 = nullptr;
    const int4* idxz = nullptr;
    const float4* w4z = nullptr;

    if constexpr (MODE == G_CONV) {
        Az = xpad + (size_t)z * PPIX * CDIM; B1 = Wt; Nrows = 768; ntap = 9;
    } else if constexpr (MODE == G_DEFORM) {
        Az = xpad + (size_t)z * PPIX * CDIM; B1 = Wt; Nrows = 768; ntap = 9;
        idxz = idx4 + (size_t)z * 9 * 4096;
        w4z = w4 + (size_t)z * 9 * 4096;
    } else if constexpr (MODE == G_PROJ) {
        Ac = blkA + (size_t)z * HW * CDIM;            // sub0: BN'd block output
        Az = xpad + (size_t)z * PPIX * CDIM;          // sub1: original x (center tap)
        B1 = pp.b1[z]; B2 = pp.b2[z];
        Nrows = pp.ch[z]; choff = pp.choff[z];
        ntap = B2 ? 2 : 1;
        if (n0 >= Nrows) return;
    } else { // G_SPAT
        Ac = blkA; B1 = Wt; Nrows = 384; ntap = 1; ldo = 384;
        if (n0 >= Nrows) return;
    }

    __shared__ __align__(16) u16 As[2][128 * 32];
    __shared__ __align__(16) u16 Bs[2][256 * 32];

    const int t = threadIdx.x;
    const int lane = t & 63;
    const int wid = t >> 6;
    const int wrow = (wid >> 1) * 64, wcol = (wid & 1) * 128;
    const int lm = lane & 15;
    const int quad = lane >> 4;

    // staging geometry (gl16 linear order)
    int rA[2], csA[2], rB[4], csB[4];
#pragma unroll
    for (int c = 0; c < 2; c++) {
        rA[c] = c * 64 + (t >> 2);
        csA[c] = (t & 3) ^ swz(rA[c]);
    }
#pragma unroll
    for (int c = 0; c < 4; c++) {
        rB[c] = c * 64 + (t >> 2);
        csB[c] = (t & 3) ^ swz(rB[c]);
    }

    f32x4 acc[4][8];
#pragma unroll
    for (int i = 0; i < 4; i++)
#pragma unroll
        for (int j = 0; j < 8; j++) acc[i][j] = (f32x4){0.f, 0.f, 0.f, 0.f};

    const int totS = ntap * 24;

    // loop-carried staging state
    const u16* aP[2];
    const u16* bP[4];
    int dOff[2][4];          // deform: byte offsets (iv + chunk) vs Az
    float4 wv[2];

    auto setupSub = [&](int sn) {
        const u16* Bb;
        if constexpr (MODE == G_CONV || MODE == G_DEFORM)
            Bb = B1 + (size_t)sn * CDIM * CDIM;
        else if constexpr (MODE == G_PROJ)
            Bb = (sn == 0) ? B1 : B2;
        else
            Bb = B1;
#pragma unroll
        for (int c = 0; c < 4; c++) bP[c] = Bb + (size_t)(n0 + rB[c]) * CDIM + csB[c] * 8;

        if constexpr (MODE == G_DEFORM) {
#pragma unroll
            for (int c = 0; c < 2; c++) {
                int4 iv = idxz[sn * 4096 + m0 + rA[c]];
                wv[c] = w4z[sn * 4096 + m0 + rA[c]];
                dOff[c][0] = (iv.x + csA[c] * 8) * 2;
                dOff[c][1] = (iv.y + csA[c] * 8) * 2;
                dOff[c][2] = (iv.z + csA[c] * 8) * 2;
                dOff[c][3] = (iv.w + csA[c] * 8) * 2;
            }
        } else if constexpr (MODE == G_CONV) {
            int ky = sn / 3, kx = sn % 3;
#pragma unroll
            for (int c = 0; c < 2; c++) {
                int p = m0 + rA[c];
                int pidx = ((p >> 6) + ky) * 66 + (p & 63) + kx;
                aP[c] = Az + (size_t)pidx * CDIM + csA[c] * 8;
            }
        } else if constexpr (MODE == G_PROJ) {
#pragma unroll
            for (int c = 0; c < 2; c++) {
                int p = m0 + rA[c];
                if (sn == 1) {
                    int pidx = ((p >> 6) + 1) * 66 + (p & 63) + 1;
                    aP[c] = Az + (size_t)pidx * CDIM + csA[c] * 8;
                } else {
                    aP[c] = Ac + (size_t)p * CDIM + csA[c] * 8;
                }
            }
        } else {
#pragma unroll
            for (int c = 0; c < 2; c++)
                aP[c] = Ac + (size_t)(m0 + rA[c]) * CDIM + csA[c] * 8;
        }
    };

    auto blend4 = [&](const uint4* L, float4 w) -> uint4 {
        auto bl = [&](unsigned a, unsigned b, unsigned c2, unsigned d) -> unsigned {
            float lo = w.x * lof(a) + w.y * lof(b) + w.z * lof(c2) + w.w * lof(d);
            float hi = w.x * hif(a) + w.y * hif(b) + w.z * hif(c2) + w.w * hif(d);
            return pkbf(lo, hi);
        };
        uint4 o;
        o.x = bl(L[0].x, L[1].x, L[2].x, L[3].x);
        o.y = bl(L[0].y, L[1].y, L[2].y, L[3].y);
        o.z = bl(L[0].z, L[1].z, L[2].z, L[3].z);
        o.w = bl(L[0].w, L[1].w, L[2].w, L[3].w);
        return o;
    };

    setupSub(0);
    int stagedSub = 0;

    // ---- prologue: stage step 0 into buf 0 (latency exposed once) ----
    {
        if constexpr (MODE == G_DEFORM) {
            uint4 L[2][4];
#pragma unroll
            for (int c = 0; c < 2; c++)
#pragma unroll
                for (int k = 0; k < 4; k++)
                    L[c][k] = *(const uint4*)((const char*)Az + dOff[c][k]);
#pragma unroll
            for (int c = 0; c < 2; c++) {
                uint4 o = blend4(L[c], wv[c]);
                *(uint4*)&As[0][(c * 4 + wid) * 512 + lane * 8] = o;
            }
        } else {
            gl16(aP[0], &As[0][(0 * 4 + wid) * 512]);
            gl16(aP[1], &As[0][(1 * 4 + wid) * 512]);
        }
#pragma unroll
        for (int c = 0; c < 4; c++) gl16(bP[c], &Bs[0][(c * 4 + wid) * 512]);
    }

    for (int s = 0; s < totS; ++s) {
        const int cur = s & 1;
        const int nxt = cur ^ 1;
        __syncthreads();
        const bool hasN = (s + 1 < totS);
        uint4 L[2][4];
        if (hasN) {
            int kn = (s + 1) - stagedSub * 24;
            if (kn == 24) { setupSub(++stagedSub); kn = 0; }
            const int cbn = kn * 32;
            if constexpr (MODE == G_DEFORM) {
#pragma unroll
                for (int c = 0; c < 2; c++)
#pragma unroll
                    for (int k = 0; k < 4; k++)
                        L[c][k] = *(const uint4*)((const char*)Az + dOff[c][k] + cbn * 2);
            } else {
                gl16(aP[0] + cbn, &As[nxt][(0 * 4 + wid) * 512]);
                gl16(aP[1] + cbn, &As[nxt][(1 * 4 + wid) * 512]);
            }
#pragma unroll
            for (int c = 0; c < 4; c++) gl16(bP[c] + cbn, &Bs[nxt][(c * 4 + wid) * 512]);
        }
        // ---- A frags from cur ----
        short8 af[4];
#pragma unroll
        for (int i = 0; i < 4; i++) {
            int rr = wrow + i * 16 + lm;
            af[i] = *(const short8*)&As[cur][rr * 32 + ((quad ^ swz(rr)) * 8)];
        }
        if constexpr (MODE == G_DEFORM) {
            if (hasN) {
                uint4 o = blend4(L[0], wv[0]);
                *(uint4*)&As[nxt][(0 * 4 + wid) * 512 + lane * 8] = o;
            }
        }
        // ---- B frags from cur ----
        short8 bf[8];
#pragma unroll
        for (int j = 0; j < 8; j++) {
            int rr = wcol + j * 16 + lm;
            bf[j] = *(const short8*)&Bs[cur][rr * 32 + ((quad ^ swz(rr)) * 8)];
        }
        if constexpr (MODE == G_DEFORM) {
            if (hasN) {
                uint4 o = blend4(L[1], wv[1]);
                *(uint4*)&As[nxt][(1 * 4 + wid) * 512 + lane * 8] = o;
            }
        }
        // ---- MFMA ----
#pragma unroll
        for (int i = 0; i < 4; i++)
#pragma unroll
            for (int j = 0; j < 8; j++)
                acc[i][j] = __builtin_amdgcn_mfma_f32_16x16x32_bf16(af[i], bf[j], acc[i][j], 0, 0, 0);
    }

    // ---- epilogue ----
    if constexpr (MODE == G_CONV || MODE == G_DEFORM) {
        u16* outz = outb + (size_t)z * HW * CDIM;
#pragma unroll
        for (int j = 0; j < 8; j++) {
            int gc = n0 + wcol + j * 16 + lm;
            float bv = bias[gc];
#pragma unroll
            for (int i = 0; i < 4; i++)
#pragma unroll
                for (int r = 0; r < 4; r++) {
                    int gr = m0 + wrow + i * 16 + quad * 4 + r;
                    outz[(size_t)gr * CDIM + gc] = f2bf(acc[i][j][r] + bv);
                }
        }
    } else {
#pragma unroll
        for (int j = 0; j < 8; j++) {
            int gc = n0 + wcol + j * 16 + lm;
            if (gc < Nrows) {
#pragma unroll
                for (int i = 0; i < 4; i++)
#pragma unroll
                    for (int r = 0; r < 4; r++) {
                        int gr = m0 + wrow + i * 16 + quad * 4 + r;
                        outf[(size_t)gr * ldo + choff + gc] = acc[i][j][r];
                    }
            }
        }
    }
}

// ---------------------------------------------------------------- prep kernels
struct Ptr5 { const float* p[5]; };

// build zero-padded bf16 image [5][66][66][768]
__global__ void k_prep_xpad(Ptr5 xs, u16* __restrict__ xpad) {
    int z = blockIdx.y;
    int pidx = blockIdx.x;
    int ph = pidx / 66, pw = pidx - ph * 66;
    int e0 = threadIdx.x * 4;
    u16* d = xpad + ((size_t)z * PPIX + pidx) * CDIM + e0;
    if (ph == 0 || ph == 65 || pw == 0 || pw == 65) {
        *(uint2*)d = make_uint2(0, 0);
        return;
    }
    const float* s = xs.p[z] + ((size_t)((ph - 1) * 64 + (pw - 1))) * CDIM + e0;
    float4 v = *(const float4*)s;
    u16 o[4] = {f2bf(v.x), f2bf(v.y), f2bf(v.z), f2bf(v.w)};
    *(uint2*)d = *(uint2*)o;
}

__global__ void k_prep_wt(const float* __restrict__ cw, u16* __restrict__ Wt) {
    int o = blockIdx.x;
    for (int c = threadIdx.x; c < 768; c += 256) {
        const float* s = cw + ((size_t)o * 768 + c) * 9;
#pragma unroll
        for (int k = 0; k < 9; k++)
            Wt[(size_t)k * 768 * 768 + (size_t)o * 768 + c] = f2bf(s[k]);
    }
}

struct WbP { const float* src[9]; u16* dst[9]; int n[9]; };

__global__ void k_prep_wb(WbP wp) {
    int m = blockIdx.y;
    int i = (blockIdx.x * 256 + threadIdx.x) * 4;
    if (i >= wp.n[m]) return;
    float4 v = *(const float4*)(wp.src[m] + i);
    u16* d = wp.dst[m] + i;
    d[0] = f2bf(v.x); d[1] = f2bf(v.y); d[2] = f2bf(v.z); d[3] = f2bf(v.w);
}

// ---------------------------------------------------------------- offset / mask
__global__ void k_offmask1(const u16* __restrict__ om, const float* __restrict__ off_w,
                           const float* __restrict__ off_b, const float* __restrict__ msk_w,
                           const float* __restrict__ msk_b, float* __restrict__ offs,
                           float* __restrict__ msoft) {
    int z = blockIdx.y;
    int wid = threadIdx.x >> 6, lane = threadIdx.x & 63;
    int p = blockIdx.x * 4 + wid;
    const u16* r = om + (size_t)z * HW * CDIM + (size_t)p * CDIM;
    float v[12];
#pragma unroll
    for (int j = 0; j < 12; j++) v[j] = bf2f(r[lane + 64 * j]);
    float lg[9];
#pragma unroll
    for (int qq = 0; qq < 27; qq++) {
        const float* wr = (qq < 18) ? (off_w + qq * 768) : (msk_w + (qq - 18) * 768);
        float s = 0.f;
#pragma unroll
        for (int j = 0; j < 12; j++) s += v[j] * wr[lane + 64 * j];
#pragma unroll
        for (int o = 32; o > 0; o >>= 1) s += __shfl_xor(s, o, 64);
        if (qq < 18) {
            if (lane == qq) offs[((size_t)z * HW + p) * 18 + qq] = s + off_b[qq];
        } else {
            lg[qq - 18] = s + msk_b[qq - 18];
        }
    }
    float mx = -1e30f;
#pragma unroll
    for (int j = 0; j < 9; j++) mx = fmaxf(mx, lg[j]);
    float sum = 0.f;
#pragma unroll
    for (int j = 0; j < 9; j++) { lg[j] = expf(lg[j] - mx); sum += lg[j]; }
    float inv = 1.f / sum;
#pragma unroll
    for (int j = 0; j < 9; j++)
        if (lane == j) msoft[(size_t)z * 36864 + p * 9 + j] = lg[j] * inv;
}

__device__ __forceinline__ int cidx(int y, int x) {
    int yc = min(max(y, 0), 63), xc = min(max(x, 0), 63);
    return ((yc + 1) * 66 + (xc + 1)) * CDIM;   // padded-image offset
}
__device__ __forceinline__ float cval(int y, int x) {
    return (y >= 0 && y < 64 && x >= 0 && x < 64) ? 1.f : 0.f;
}

__global__ void k_offmask2(const float* __restrict__ offs, const float* __restrict__ msoft,
                           int4* __restrict__ idx4o, float4* __restrict__ w4o) {
    int id = blockIdx.x * 256 + threadIdx.x;
    int z = id / 36864, r = id % 36864, k = r >> 12, p = r & 4095;
    const float* ofz = offs + ((size_t)z * HW + p) * 18;
    float dy = ofz[2 * k], dx = ofz[2 * k + 1];
    float mk = msoft[(size_t)z * 36864 + k * 4096 + p];
    int h = p >> 6, w = p & 63;
    float py = (float)(h - 1 + k / 3) + dy;
    float px = (float)(w - 1 + k % 3) + dx;
    float y0f = floorf(py), x0f = floorf(px);
    int y0 = (int)y0f, x0 = (int)x0f;
    float wy1 = py - y0f, wx1 = px - x0f, wy0 = 1.f - wy1, wx0 = 1.f - wx1;
    idx4o[id] = make_int4(cidx(y0, x0), cidx(y0, x0 + 1), cidx(y0 + 1, x0), cidx(y0 + 1, x0 + 1));
    w4o[id] = make_float4(wy0 * wx0 * cval(y0, x0) * mk, wy0 * wx1 * cval(y0, x0 + 1) * mk,
                          wy1 * wx0 * cval(y0 + 1, x0) * mk, wy1 * wx1 * cval(y0 + 1, x0 + 1) * mk);
}

// ---------------------------------------------------------------- batchnorm
__global__ void k_bnstats(const u16* __restrict__ dout, float* __restrict__ mu,
                          float* __restrict__ rs) {
    int z = blockIdx.y;
    int c = blockIdx.x * 64 + threadIdx.x;
    int ty = threadIdx.y;
    const u16* d = dout + (size_t)z * HW * CDIM + c;
    float s1 = 0.f, s2 = 0.f;
    for (int p = ty; p < 4096; p += 8) {
        float v = bf2f(d[(size_t)p * CDIM]);
        s1 += v; s2 += v * v;
    }
    __shared__ float l1[8][64], l2[8][64];
    l1[ty][threadIdx.x] = s1; l2[ty][threadIdx.x] = s2;
    __syncthreads();
    if (ty == 0) {
        for (int y = 1; y < 8; y++) { s1 += l1[y][threadIdx.x]; s2 += l2[y][threadIdx.x]; }
        float m = s1 / 4096.f;
        float var = s2 / 4096.f - m * m;
        mu[z * 768 + c] = m;
        rs[z * 768 + c] = rsqrtf(var + 1e-5f);
    }
}

__global__ void k_bnapply(const u16* __restrict__ dout, const float* __restrict__ mu,
                          const float* __restrict__ rs, const float* __restrict__ g,
                          const float* __restrict__ b, u16* __restrict__ blk) {
    size_t i = ((size_t)blockIdx.x * 256 + threadIdx.x) * 8;
    int c = (int)(i % CDIM);
    int z = (int)(i / ((size_t)HW * CDIM));
    const float* muz = mu + z * 768;
    const float* rsz = rs + z * 768;
    uint4 in = *(const uint4*)(dout + i);
    const u16* u = (const u16*)&in;
    u16 o[8];
#pragma unroll
    for (int e = 0; e < 8; e++) {
        int ce = c + e;
        float v = (bf2f(u[e]) - muz[ce]) * rsz[ce] * g[ce] + b[ce];
        o[e] = f2bf(fmaxf(v, 0.f));
    }
    *(uint4*)(blk + i) = *(uint4*)o;
}

// ---------------------------------------------------------------- CAM
__global__ void k_q(const float* __restrict__ X, const float* __restrict__ chq,
                    float* __restrict__ q) {
    int wid = threadIdx.x >> 6, lane = threadIdx.x & 63;
    int p = blockIdx.x * 4 + wid;
    const float* xr = X + (size_t)p * CDIM;
    float s = 0.f;
#pragma unroll
    for (int j = 0; j < 12; j++) s += xr[lane + 64 * j] * chq[lane + 64 * j];
#pragma unroll
    for (int o = 32; o > 0; o >>= 1) s += __shfl_xor(s, o, 64);
    if (lane == 0) q[p] = s;
}

__global__ void k_soft4096(const float* __restrict__ q, float* __restrict__ sqn,
                           float* __restrict__ xq) {
    __shared__ float red[4];
    int tid = threadIdx.x, lane = tid & 63, wid = tid >> 6;
    float m = -1e30f;
    for (int i = tid; i < 4096; i += 256) m = fmaxf(m, q[i]);
    for (int o = 32; o > 0; o >>= 1) m = fmaxf(m, __shfl_xor(m, o, 64));
    if (lane == 0) red[wid] = m;
    __syncthreads();
    float bm = fmaxf(fmaxf(red[0], red[1]), fmaxf(red[2], red[3]));
    __syncthreads();
    float s = 0.f;
    for (int i = tid; i < 4096; i += 256) {
        float e = expf(q[i] - bm);
        sqn[i] = e; s += e;
    }
    for (int o = 32; o > 0; o >>= 1) s += __shfl_xor(s, o, 64);
    if (lane == 0) red[wid] = s;
    __syncthreads();
    float inv = 1.f / (red[0] + red[1] + red[2] + red[3]);
    for (int i = tid; i < 4096; i += 256) sqn[i] *= inv;
    for (int c = tid; c < 768; c += 256) xq[c] = 0.f;
}

__global__ void k_xq(const float* __restrict__ X, const float* __restrict__ sqn,
                     float* __restrict__ xq) {
    int p0 = blockIdx.x * 512;
    for (int c = threadIdx.x; c < 768; c += 256) {
        float a = 0.f;
        for (int p = p0; p < p0 + 512; p++) a += sqn[p] * X[(size_t)p * CDIM + c];
        atomicAdd(&xq[c], a);
    }
}

__global__ void k_cam4(const float* __restrict__ chv, const float* __restrict__ chz,
                       const float* __restrict__ xq, const float* __restrict__ lng,
                       const float* __restrict__ lnb, float* __restrict__ sgate) {
    __shared__ float wvq[384];
    __shared__ float wzv[768];
    __shared__ float red[12];
    int tid = threadIdx.x, lane = tid & 63, wid = tid >> 6;
    {
        float s = 0.f;
        const float* r = chv + (size_t)tid * 768;
        for (int j = 0; j < 768; j++) s += r[j] * xq[j];
        wvq[tid] = s;
    }
    __syncthreads();
    for (int c = tid; c < 768; c += 384) {
        float s = 0.f;
        const float* r = chz + (size_t)c * 384;
        for (int o = 0; o < 384; o++) s += r[o] * wvq[o];
        wzv[c] = s;
    }
    __syncthreads();
    float a = wzv[tid], b = wzv[tid + 384];
    float s1 = a + b, s2 = a * a + b * b;
    for (int o = 32; o > 0; o >>= 1) { s1 += __shfl_xor(s1, o, 64); s2 += __shfl_xor(s2, o, 64); }
    if (lane == 0) { red[wid] = s1; red[6 + wid] = s2; }
    __syncthreads();
    s1 = 0.f; s2 = 0.f;
    for (int w = 0; w < 6; w++) { s1 += red[w]; s2 += red[6 + w]; }
    float mean = s1 / 768.f, var = s2 / 768.f - mean * mean, rstd = rsqrtf(var + 1e-5f);
    for (int c = tid; c < 768; c += 384) {
        float t = (wzv[c] - mean) * rstd * lng[c] + lnb[c];
        sgate[c] = 1.f / (1.f + expf(-t));
    }
}

__global__ void k_xatt(const float* __restrict__ X, const float* __restrict__ sgate,
                       u16* __restrict__ xatt) {
    size_t i = ((size_t)blockIdx.x * 256 + threadIdx.x) * 4;
    int c = (int)(i % CDIM);
    float4 v = *(const float4*)(X + i);
    u16 o[4] = {f2bf(v.x * sgate[c]), f2bf(v.y * sgate[c + 1]),
                f2bf(v.z * sgate[c + 2]), f2bf(v.w * sgate[c + 3])};
    *(uint2*)(xatt + i) = *(uint2*)o;
}

__global__ void k_colmax(const float* __restrict__ P2, float* __restrict__ m2) {
    __shared__ float red[8][64];
    int o = blockIdx.x * 64 + threadIdx.x;
    float m = -1e30f;
    for (int p = threadIdx.y; p < 4096; p += 8) m = fmaxf(m, P2[(size_t)p * 384 + o]);
    red[threadIdx.y][threadIdx.x] = m;
    __syncthreads();
    if (threadIdx.y == 0) {
        for (int y = 1; y < 8; y++) m = fmaxf(m, red[y][threadIdx.x]);
        m2[o] = m;
    }
}

__global__ void k_cam7(const float* __restrict__ m2, const float* __restrict__ spv,
                       float* __restrict__ sv) {
    __shared__ float sq2[384];
    __shared__ float red[6];
    int tid = threadIdx.x, lane = tid & 63, wid = tid >> 6;
    float v = m2[tid];
    float m = v;
    for (int o = 32; o > 0; o >>= 1) m = fmaxf(m, __shfl_xor(m, o, 64));
    if (lane == 0) red[wid] = m;
    __syncthreads();
    m = red[0];
    for (int w = 1; w < 6; w++) m = fmaxf(m, red[w]);
    __syncthreads();
    float e = expf(v - m);
    float s = e;
    for (int o = 32; o > 0; o >>= 1) s += __shfl_xor(s, o, 64);
    if (lane == 0) red[wid] = s;
    __syncthreads();
    float tot = 0.f;
    for (int w = 0; w < 6; w++) tot += red[w];
    sq2[tid] = e / tot;
    __syncthreads();
    for (int c = tid; c < 768; c += 384) {
        float a = 0.f;
        for (int o = 0; o < 384; o++) a += sq2[o] * spv[(size_t)o * 768 + c];
        sv[c] = a;
    }
}

__global__ void k_final(const float* __restrict__ X, const float* __restrict__ x5,
                        const float* __restrict__ sgate, const float* __restrict__ sv,
                        const float* __restrict__ ng, const float* __restrict__ nb,
                        float* __restrict__ out) {
    int wid = threadIdx.x >> 6, lane = threadIdx.x & 63;
    int p = blockIdx.x * 4 + wid;
    const float* xr = X + (size_t)p * CDIM;
    const float* x5r = x5 + (size_t)p * CDIM;
    float xa[12];
    float d = 0.f;
#pragma unroll
    for (int j = 0; j < 12; j++) {
        int c = lane + 64 * j;
        float a = xr[c] * sgate[c];
        xa[j] = a;
        d += sv[c] * a;
    }
#pragma unroll
    for (int o = 32; o > 0; o >>= 1) d += __shfl_xor(d, o, 64);
    float wz2 = 1.f / (1.f + expf(-d));
    float s1 = 0.f, s2 = 0.f;
#pragma unroll
    for (int j = 0; j < 12; j++) {
        int c = lane + 64 * j;
        float y = wz2 * xa[j] + xr[c] + x5r[c];
        xa[j] = y;
        s1 += y; s2 += y * y;
    }
#pragma unroll
    for (int o = 32; o > 0; o >>= 1) { s1 += __shfl_xor(s1, o, 64); s2 += __shfl_xor(s2, o, 64); }
    float mean = s1 / 768.f, var = s2 / 768.f - mean * mean, rstd = rsqrtf(var + 1e-5f);
#pragma unroll
    for (int j = 0; j < 12; j++) {
        int c = lane + 64 * j;
        out[(size_t)p * CDIM + c] = (xa[j] - mean) * rstd * ng[c] + nb[c];
    }
}

// ---------------------------------------------------------------- launch
extern "C" void kernel_launch(void* const* d_in, const int* in_sizes, int n_in,
                              void* d_out, int out_size, void* d_ws, size_t ws_size,
                              hipStream_t stream) {
    const float* xin[5];
    for (int i = 0; i < 5; i++) xin[i] = (const float*)d_in[i];
    const float* conv_w = (const float*)d_in[5];
    const float* conv_b = (const float*)d_in[6];
    const float* off_w = (const float*)d_in[7];
    const float* off_b = (const float*)d_in[8];
    const float* msk_w = (const float*)d_in[9];
    const float* msk_b = (const float*)d_in[10];
    const float* bn_g = (const float*)d_in[11];
    const float* bn_b = (const float*)d_in[12];
    const float* chq_w = (const float*)d_in[13];
    const float* chv_w = (const float*)d_in[14];
    const float* chz_w = (const float*)d_in[15];
    const float* ln_g = (const float*)d_in[16];
    const float* ln_b = (const float*)d_in[17];
    const float* spq_w = (const float*)d_in[18];
    const float* spv_w = (const float*)d_in[19];
    const float* wsrc[8];
    for (int i = 0; i < 8; i++) wsrc[i] = (const float*)d_in[20 + i];
    const float* norm_g = (const float*)d_in[28];
    const float* norm_b = (const float*)d_in[29];
    float* out = (float*)d_out;

    char* wsb = (char*)d_ws;
    size_t off = 0;
    auto take = [&](size_t n) -> char* {
        char* p = wsb + off;
        off = (off + n + 255) & ~(size_t)255;
        return p;
    };
    u16* xpad = (u16*)take(5ll * PPIX * CDIM * 2);
    u16* Wt = (u16*)take(9ll * CDIM * CDIM * 2);
    u16* omblk = (u16*)take(5ll * HW * CDIM * 2);  // om, later reused as blk
    float* offs = (float*)take(5ll * HW * 18 * 4);
    float* msoft = (float*)take(5ll * 36864 * 4);
    int4* idx4 = (int4*)take(5ll * 9 * 4096 * 16);
    float4* w4 = (float4*)take(5ll * 9 * 4096 * 16);
    u16* dout = (u16*)take(5ll * HW * CDIM * 2);   // later reused: xatt @+0, P2 @+8MB
    u16* wb = (u16*)take(1790ll * 768 * 2);
    float* Xcat = (float*)take((size_t)HW * CDIM * 4);
    float* mu = (float*)take(5 * 768 * 4);
    float* rs = (float*)take(5 * 768 * 4);
    float* qv = (float*)take(4096 * 4);
    float* sqn = (float*)take(4096 * 4);
    float* xq = (float*)take(768 * 4);
    float* sgate = (float*)take(768 * 4);
    float* m2 = (float*)take(384 * 4);
    float* sv = (float*)take(768 * 4);
    u16* xatt = dout;
    float* P2 = (float*)((char*)dout + 8388608);
    u16* blk = omblk;
    (void)ws_size; (void)in_sizes; (void)n_in; (void)out_size;

    int rows[9] = {30, 100, 150, 150, 220, 220, 268, 268, 384};
    int roff[9]; int acc = 0;
    for (int i = 0; i < 9; i++) { roff[i] = acc; acc += rows[i]; }
    u16* spqb = wb + (size_t)roff[8] * 768;

    WbP wp;
    for (int i = 0; i < 8; i++) { wp.src[i] = wsrc[i]; wp.dst[i] = wb + (size_t)roff[i] * 768; wp.n[i] = rows[i] * 768; }
    wp.src[8] = spq_w; wp.dst[8] = spqb; wp.n[8] = rows[8] * 768;

    ProjP pp;
    pp.b1[0] = wb + (size_t)roff[0] * 768; pp.b2[0] = nullptr;
    pp.b1[1] = wb + (size_t)roff[1] * 768; pp.b2[1] = nullptr;
    pp.b1[2] = wb + (size_t)roff[2] * 768; pp.b2[2] = wb + (size_t)roff[3] * 768;
    pp.b1[3] = wb + (size_t)roff[4] * 768; pp.b2[3] = wb + (size_t)roff[5] * 768;
    pp.b1[4] = wb + (size_t)roff[6] * 768; pp.b2[4] = wb + (size_t)roff[7] * 768;
    int chs[5] = {30, 100, 150, 220, 268};
    int cof[5] = {0, 30, 130, 280, 500};
    for (int i = 0; i < 5; i++) { pp.ch[i] = chs[i]; pp.choff[i] = cof[i]; }
    ProjP pdum = {};

    Ptr5 xs;
    for (int i = 0; i < 5; i++) xs.p[i] = xin[i];

    // ---- prep ----
    k_prep_xpad<<<dim3(PPIX, 5), 192, 0, stream>>>(xs, xpad);
    k_prep_wt<<<dim3(768), 256, 0, stream>>>(conv_w, Wt);
    k_prep_wb<<<dim3(288, 9), 256, 0, stream>>>(wp);

    // ---- per-level heavy path (batched over z=5) ----
    k_gemm<G_CONV><<<dim3(32, 3, 5), 256, 0, stream>>>(xpad, nullptr, Wt, nullptr, nullptr,
                                                       conv_b, omblk, nullptr, pdum);
    k_offmask1<<<dim3(1024, 5), 256, 0, stream>>>(omblk, off_w, off_b, msk_w, msk_b, offs, msoft);
    k_offmask2<<<dim3(720), 256, 0, stream>>>(offs, msoft, idx4, w4);
    k_gemm<G_DEFORM><<<dim3(32, 3, 5), 256, 0, stream>>>(xpad, nullptr, Wt, idx4, w4,
                                                         conv_b, dout, nullptr, pdum);
    k_bnstats<<<dim3(12, 5), dim3(64, 8), 0, stream>>>(dout, mu, rs);
    k_bnapply<<<dim3(7680), 256, 0, stream>>>(dout, mu, rs, bn_g, bn_b, blk);
    k_gemm<G_PROJ><<<dim3(32, 2, 5), 256, 0, stream>>>(xpad, blk, nullptr, nullptr, nullptr,
                                                       nullptr, nullptr, Xcat, pp);

    // ---- CAM ----
    k_q<<<dim3(1024), 256, 0, stream>>>(Xcat, chq_w, qv);
    k_soft4096<<<dim3(1), 256, 0, stream>>>(qv, sqn, xq);
    k_xq<<<dim3(8), 256, 0, stream>>>(Xcat, sqn, xq);
    k_cam4<<<dim3(1), 384, 0, stream>>>(chv_w, chz_w, xq, ln_g, ln_b, sgate);
    k_xatt<<<dim3(3072), 256, 0, stream>>>(Xcat, sgate, xatt);
    k_gemm<G_SPAT><<<dim3(32, 2, 1), 256, 0, stream>>>(xpad, xatt, spqb, nullptr, nullptr,
                                                       nullptr, nullptr, P2, pdum);
    k_colmax<<<dim3(6), dim3(64, 8), 0, stream>>>(P2, m2);
    k_cam7<<<dim3(1), 384, 0, stream>>>(m2, spv_w, sv);

    // ---- residual + final LayerNorm ----
    k_final<<<dim3(1024), 256, 0, stream>>>(Xcat, xin[4], sgate, sv, norm_g, norm_b, out);
}

// Round 4
// 1202.841 us; speedup vs baseline: 1.2072x; 1.2072x over previous
//
#include <hip/hip_runtime.h>
#include <cstdint>
#include <cstddef>

#define HW 4096
#define CDIM 768
#define PPIX 4356   // 66*66 padded pixels

typedef unsigned short u16;
typedef __attribute__((ext_vector_type(8))) short short8;
typedef __attribute__((ext_vector_type(4))) float f32x4;

__device__ __forceinline__ float bf2f(u16 u) { return __uint_as_float(((unsigned)u) << 16); }
__device__ __forceinline__ u16 f2bf(float f) {
    unsigned u = __float_as_uint(f);
    unsigned r = (u + 0x7fffu + ((u >> 16) & 1u)) >> 16;
    return (u16)r;
}
__device__ __forceinline__ float lof(unsigned u) { return __uint_as_float(u << 16); }
__device__ __forceinline__ float hif(unsigned u) { return __uint_as_float(u & 0xffff0000u); }
__device__ __forceinline__ int swz(int r) { return ((r >> 1) ^ (r >> 3)) & 3; }

__device__ __forceinline__ void gl16(const u16* g, u16* l) {
    __builtin_amdgcn_global_load_lds(
        (const __attribute__((address_space(1))) unsigned int*)g,
        (__attribute__((address_space(3))) unsigned int*)l, 16, 0, 0);
}

enum GMode { G_CONV = 0, G_PROJ = 2, G_SPAT = 3 };

struct ProjP {
    const u16* b1[5];
    const u16* b2[5];
    int ch[5];
    int choff[5];
};

// ---------------------------------------------------------------- 128x128 GEMM
// m97-shape: single LDS buffer (16KB), 2 barriers/step, 4 blocks/CU.
// K-order: kk-outer, tap-inner (L2 window ~2MB for concurrent blocks).
template <int MODE>
__launch_bounds__(256, 4)
__global__ void k_gemm128(const u16* __restrict__ xpad, const u16* __restrict__ blkA,
                          const u16* __restrict__ Wt, const float* __restrict__ bias,
                          u16* __restrict__ outb, float* __restrict__ outf, ProjP pp) {
    const int z = blockIdx.z;
    const int m0 = blockIdx.x * 128;
    const int n0 = blockIdx.y * 128;

    int Nrows, ntap, choff = 0, ldo = CDIM;
    const u16 *Az = nullptr, *Ac = nullptr, *B1 = nullptr, *B2 = nullptr;
    if constexpr (MODE == G_CONV) {
        Az = xpad + (size_t)z * PPIX * CDIM; B1 = Wt; Nrows = 768; ntap = 9;
    } else if constexpr (MODE == G_PROJ) {
        Ac = blkA + (size_t)z * HW * CDIM;
        Az = xpad + (size_t)z * PPIX * CDIM;
        B1 = pp.b1[z]; B2 = pp.b2[z];
        Nrows = pp.ch[z]; choff = pp.choff[z];
        ntap = B2 ? 2 : 1;
        if (n0 >= Nrows) return;
    } else { // G_SPAT
        Ac = blkA; B1 = Wt; Nrows = 384; ntap = 1; ldo = 384;
    }

    __shared__ __align__(16) u16 As[128 * 32];
    __shared__ __align__(16) u16 Bs[128 * 32];

    const int t = threadIdx.x;
    const int lane = t & 63;
    const int wid = t >> 6;
    const int wrow = (wid >> 1) * 64, wcol = (wid & 1) * 64;
    const int lm = lane & 15;
    const int quad = lane >> 4;

    const int rS = t >> 2;
    const int cs0 = (t & 3) ^ swz(rS);
    const int cs1 = (t & 3) ^ swz(64 + rS);

    // A base pointers (element units)
    const u16 *a0 = nullptr, *a1 = nullptr, *a0x = nullptr, *a1x = nullptr;
    if constexpr (MODE == G_CONV) {
        int p0 = m0 + rS, p1 = m0 + 64 + rS;
        a0 = Az + (size_t)(((p0 >> 6)) * 66 + (p0 & 63)) * CDIM + cs0 * 8;
        a1 = Az + (size_t)(((p1 >> 6)) * 66 + (p1 & 63)) * CDIM + cs1 * 8;
    } else if constexpr (MODE == G_PROJ) {
        int p0 = m0 + rS, p1 = m0 + 64 + rS;
        a0 = Ac + (size_t)p0 * CDIM + cs0 * 8;
        a1 = Ac + (size_t)p1 * CDIM + cs1 * 8;
        a0x = Az + (size_t)(((p0 >> 6) + 1) * 66 + (p0 & 63) + 1) * CDIM + cs0 * 8;
        a1x = Az + (size_t)(((p1 >> 6) + 1) * 66 + (p1 & 63) + 1) * CDIM + cs1 * 8;
    } else {
        a0 = Ac + (size_t)(m0 + rS) * CDIM + cs0 * 8;
        a1 = Ac + (size_t)(m0 + 64 + rS) * CDIM + cs1 * 8;
    }
    // B base pointers
    const u16* b0 = B1 + (size_t)(n0 + rS) * CDIM + cs0 * 8;
    const u16* b1p = B1 + (size_t)(n0 + 64 + rS) * CDIM + cs1 * 8;
    const u16 *c0 = nullptr, *c1 = nullptr;
    if constexpr (MODE == G_PROJ) {
        if (B2) {
            c0 = B2 + (size_t)(n0 + rS) * CDIM + cs0 * 8;
            c1 = B2 + (size_t)(n0 + 64 + rS) * CDIM + cs1 * 8;
        }
    }

    u16* dA0 = &As[(0 * 4 + wid) * 512];
    u16* dA1 = &As[(1 * 4 + wid) * 512];
    u16* dB0 = &Bs[(0 * 4 + wid) * 512];
    u16* dB1 = &Bs[(1 * 4 + wid) * 512];

    f32x4 acc[4][4];
#pragma unroll
    for (int i = 0; i < 4; i++)
#pragma unroll
        for (int j = 0; j < 4; j++) acc[i][j] = (f32x4){0.f, 0.f, 0.f, 0.f};

    const int totS = ntap * 24;
    int tap = 0;
    int tA = 0, tB = 0, kO = 0;

    for (int s = 0; s < totS; ++s) {
        __syncthreads();
        if constexpr (MODE == G_CONV) {
            gl16(a0 + tA + kO, dA0);
            gl16(a1 + tA + kO, dA1);
            gl16(b0 + tB + kO, dB0);
            gl16(b1p + tB + kO, dB1);
        } else if constexpr (MODE == G_PROJ) {
            if (tap == 0) {
                gl16(a0 + kO, dA0);
                gl16(a1 + kO, dA1);
                gl16(b0 + kO, dB0);
                gl16(b1p + kO, dB1);
            } else {
                gl16(a0x + kO, dA0);
                gl16(a1x + kO, dA1);
                gl16(c0 + kO, dB0);
                gl16(c1 + kO, dB1);
            }
        } else {
            gl16(a0 + kO, dA0);
            gl16(a1 + kO, dA1);
            gl16(b0 + kO, dB0);
            gl16(b1p + kO, dB1);
        }
        __syncthreads();
        short8 af[4], bf[4];
#pragma unroll
        for (int i = 0; i < 4; i++) {
            int rr = wrow + i * 16 + lm;
            af[i] = *(const short8*)&As[rr * 32 + ((quad ^ swz(rr)) * 8)];
        }
#pragma unroll
        for (int j = 0; j < 4; j++) {
            int rr = wcol + j * 16 + lm;
            bf[j] = *(const short8*)&Bs[rr * 32 + ((quad ^ swz(rr)) * 8)];
        }
#pragma unroll
        for (int i = 0; i < 4; i++)
#pragma unroll
            for (int j = 0; j < 4; j++)
                acc[i][j] = __builtin_amdgcn_mfma_f32_16x16x32_bf16(af[i], bf[j], acc[i][j], 0, 0, 0);
        // advance (tap fastest, then kk)
        tap++;
        if constexpr (MODE == G_CONV) {
            tA += (tap == 3 || tap == 6) ? 64 * CDIM : CDIM;
            tB += CDIM * CDIM;
            if (tap == 9) { tap = 0; tA = 0; tB = 0; kO += 32; }
        } else {
            if (tap == ntap) { tap = 0; kO += 32; }
        }
    }

    // ---- epilogue ----
    if constexpr (MODE == G_CONV) {
        u16* outz = outb + (size_t)z * HW * CDIM;
#pragma unroll
        for (int j = 0; j < 4; j++) {
            int gc = n0 + wcol + j * 16 + lm;
            float bv = bias[gc];
#pragma unroll
            for (int i = 0; i < 4; i++)
#pragma unroll
                for (int r = 0; r < 4; r++) {
                    int gr = m0 + wrow + i * 16 + quad * 4 + r;
                    outz[(size_t)gr * CDIM + gc] = f2bf(acc[i][j][r] + bv);
                }
        }
    } else {
#pragma unroll
        for (int j = 0; j < 4; j++) {
            int gc = n0 + wcol + j * 16 + lm;
            if (gc < Nrows) {
#pragma unroll
                for (int i = 0; i < 4; i++)
#pragma unroll
                    for (int r = 0; r < 4; r++) {
                        int gr = m0 + wrow + i * 16 + quad * 4 + r;
                        outf[(size_t)gr * ldo + choff + gc] = acc[i][j][r];
                    }
            }
        }
    }
}

// ---------------------------------------------------------------- deform GEMM (128x256, dbuf)
__launch_bounds__(256, 2)
__global__ void k_gdef(const u16* __restrict__ xpad, const u16* __restrict__ Wt,
                       const int4* __restrict__ idx4, const float4* __restrict__ w4,
                       const float* __restrict__ bias, u16* __restrict__ outb) {
    const int z = blockIdx.z;
    const int m0 = blockIdx.x * 128;
    const int n0 = blockIdx.y * 256;
    const u16* Az = xpad + (size_t)z * PPIX * CDIM;
    const int4* idxz = idx4 + (size_t)z * 9 * 4096;
    const float4* w4z = w4 + (size_t)z * 9 * 4096;

    __shared__ __align__(16) u16 As[2][128 * 32];
    __shared__ __align__(16) u16 Bs[2][256 * 32];

    const int t = threadIdx.x;
    const int lane = t & 63;
    const int wid = t >> 6;
    const int wrow = (wid >> 1) * 64, wcol = (wid & 1) * 128;
    const int lm = lane & 15;
    const int quad = lane >> 4;

    int rA[2], csA[2], rB[4], csB[4];
#pragma unroll
    for (int c = 0; c < 2; c++) {
        rA[c] = c * 64 + (t >> 2);
        csA[c] = (t & 3) ^ swz(rA[c]);
    }
#pragma unroll
    for (int c = 0; c < 4; c++) {
        rB[c] = c * 64 + (t >> 2);
        csB[c] = (t & 3) ^ swz(rB[c]);
    }

    f32x4 acc[4][8];
#pragma unroll
    for (int i = 0; i < 4; i++)
#pragma unroll
        for (int j = 0; j < 8; j++) acc[i][j] = (f32x4){0.f, 0.f, 0.f, 0.f};

    const u16* bP[4];
    int dOff[2][4];
    float4 wv[2];

    auto setupSub = [&](int sn) {
        const u16* Bb = Wt + (size_t)sn * CDIM * CDIM;
#pragma unroll
        for (int c = 0; c < 4; c++) bP[c] = Bb + (size_t)(n0 + rB[c]) * CDIM + csB[c] * 8;
#pragma unroll
        for (int c = 0; c < 2; c++) {
            int4 iv = idxz[sn * 4096 + m0 + rA[c]];
            wv[c] = w4z[sn * 4096 + m0 + rA[c]];
            dOff[c][0] = (iv.x + csA[c] * 8) * 2;
            dOff[c][1] = (iv.y + csA[c] * 8) * 2;
            dOff[c][2] = (iv.z + csA[c] * 8) * 2;
            dOff[c][3] = (iv.w + csA[c] * 8) * 2;
        }
    };

    auto blend4 = [&](const uint4* L, float4 w) -> uint4 {
        auto bl = [&](unsigned a, unsigned b, unsigned c2, unsigned d) -> unsigned {
            float lo = w.x * lof(a) + w.y * lof(b) + w.z * lof(c2) + w.w * lof(d);
            float hi = w.x * hif(a) + w.y * hif(b) + w.z * hif(c2) + w.w * hif(d);
            return (__float_as_uint(hi) & 0xffff0000u) | (__float_as_uint(lo) >> 16);
        };
        uint4 o;
        o.x = bl(L[0].x, L[1].x, L[2].x, L[3].x);
        o.y = bl(L[0].y, L[1].y, L[2].y, L[3].y);
        o.z = bl(L[0].z, L[1].z, L[2].z, L[3].z);
        o.w = bl(L[0].w, L[1].w, L[2].w, L[3].w);
        return o;
    };

    setupSub(0);
    int stagedSub = 0;

    {   // prologue: stage step 0 into buf 0
        uint4 L[2][4];
#pragma unroll
        for (int c = 0; c < 2; c++)
#pragma unroll
            for (int k = 0; k < 4; k++)
                L[c][k] = *(const uint4*)((const char*)Az + dOff[c][k]);
#pragma unroll
        for (int c = 0; c < 2; c++) {
            uint4 o = blend4(L[c], wv[c]);
            *(uint4*)&As[0][(c * 4 + wid) * 512 + lane * 8] = o;
        }
#pragma unroll
        for (int c = 0; c < 4; c++) gl16(bP[c], &Bs[0][(c * 4 + wid) * 512]);
    }

    for (int s = 0; s < 216; ++s) {
        const int cur = s & 1;
        const int nxt = cur ^ 1;
        __syncthreads();
        const bool hasN = (s + 1 < 216);
        uint4 L[2][4];
        if (hasN) {
            int kn = (s + 1) - stagedSub * 24;
            if (kn == 24) { setupSub(++stagedSub); kn = 0; }
            const int cbn = kn * 32;
#pragma unroll
            for (int c = 0; c < 2; c++)
#pragma unroll
                for (int k = 0; k < 4; k++)
                    L[c][k] = *(const uint4*)((const char*)Az + dOff[c][k] + cbn * 2);
#pragma unroll
            for (int c = 0; c < 4; c++) gl16(bP[c] + cbn, &Bs[nxt][(c * 4 + wid) * 512]);
        }
        short8 af[4];
#pragma unroll
        for (int i = 0; i < 4; i++) {
            int rr = wrow + i * 16 + lm;
            af[i] = *(const short8*)&As[cur][rr * 32 + ((quad ^ swz(rr)) * 8)];
        }
        if (hasN) {
            uint4 o = blend4(L[0], wv[0]);
            *(uint4*)&As[nxt][(0 * 4 + wid) * 512 + lane * 8] = o;
        }
        short8 bf[8];
#pragma unroll
        for (int j = 0; j < 8; j++) {
            int rr = wcol + j * 16 + lm;
            bf[j] = *(const short8*)&Bs[cur][rr * 32 + ((quad ^ swz(rr)) * 8)];
        }
        if (hasN) {
            uint4 o = blend4(L[1], wv[1]);
            *(uint4*)&As[nxt][(1 * 4 + wid) * 512 + lane * 8] = o;
        }
#pragma unroll
        for (int i = 0; i < 4; i++)
#pragma unroll
            for (int j = 0; j < 8; j++)
                acc[i][j] = __builtin_amdgcn_mfma_f32_16x16x32_bf16(af[i], bf[j], acc[i][j], 0, 0, 0);
    }

    u16* outz = outb + (size_t)z * HW * CDIM;
#pragma unroll
    for (int j = 0; j < 8; j++) {
        int gc = n0 + wcol + j * 16 + lm;
        float bv = bias[gc];
#pragma unroll
        for (int i = 0; i < 4; i++)
#pragma unroll
            for (int r = 0; r < 4; r++) {
                int gr = m0 + wrow + i * 16 + quad * 4 + r;
                outz[(size_t)gr * CDIM + gc] = f2bf(acc[i][j][r] + bv);
            }
    }
}

// ---------------------------------------------------------------- prep kernels
struct Ptr5 { const float* p[5]; };

__global__ void k_prep_xpad(Ptr5 xs, u16* __restrict__ xpad) {
    int z = blockIdx.y;
    int pidx = blockIdx.x;
    int ph = pidx / 66, pw = pidx - ph * 66;
    int e0 = threadIdx.x * 4;
    u16* d = xpad + ((size_t)z * PPIX + pidx) * CDIM + e0;
    if (ph == 0 || ph == 65 || pw == 0 || pw == 65) {
        *(uint2*)d = make_uint2(0, 0);
        return;
    }
    const float* s = xs.p[z] + ((size_t)((ph - 1) * 64 + (pw - 1))) * CDIM + e0;
    float4 v = *(const float4*)s;
    u16 o[4] = {f2bf(v.x), f2bf(v.y), f2bf(v.z), f2bf(v.w)};
    *(uint2*)d = *(uint2*)o;
}

__global__ void k_prep_wt(const float* __restrict__ cw, u16* __restrict__ Wt) {
    int o = blockIdx.x;
    for (int c = threadIdx.x; c < 768; c += 256) {
        const float* s = cw + ((size_t)o * 768 + c) * 9;
#pragma unroll
        for (int k = 0; k < 9; k++)
            Wt[(size_t)k * 768 * 768 + (size_t)o * 768 + c] = f2bf(s[k]);
    }
}

struct WbP { const float* src[9]; u16* dst[9]; int n[9]; };

__global__ void k_prep_wb(WbP wp) {
    int m = blockIdx.y;
    int i = (blockIdx.x * 256 + threadIdx.x) * 4;
    if (i >= wp.n[m]) return;
    float4 v = *(const float4*)(wp.src[m] + i);
    u16* d = wp.dst[m] + i;
    d[0] = f2bf(v.x); d[1] = f2bf(v.y); d[2] = f2bf(v.z); d[3] = f2bf(v.w);
}

// ---------------------------------------------------------------- offset / mask
__global__ void k_offmask1(const u16* __restrict__ om, const float* __restrict__ off_w,
                           const float* __restrict__ off_b, const float* __restrict__ msk_w,
                           const float* __restrict__ msk_b, float* __restrict__ offs,
                           float* __restrict__ msoft) {
    int z = blockIdx.y;
    int wid = threadIdx.x >> 6, lane = threadIdx.x & 63;
    int p = blockIdx.x * 4 + wid;
    const u16* r = om + (size_t)z * HW * CDIM + (size_t)p * CDIM;
    float v[12];
#pragma unroll
    for (int j = 0; j < 12; j++) v[j] = bf2f(r[lane + 64 * j]);
    float lg[9];
#pragma unroll
    for (int qq = 0; qq < 27; qq++) {
        const float* wr = (qq < 18) ? (off_w + qq * 768) : (msk_w + (qq - 18) * 768);
        float s = 0.f;
#pragma unroll
        for (int j = 0; j < 12; j++) s += v[j] * wr[lane + 64 * j];
#pragma unroll
        for (int o = 32; o > 0; o >>= 1) s += __shfl_xor(s, o, 64);
        if (qq < 18) {
            if (lane == qq) offs[((size_t)z * HW + p) * 18 + qq] = s + off_b[qq];
        } else {
            lg[qq - 18] = s + msk_b[qq - 18];
        }
    }
    float mx = -1e30f;
#pragma unroll
    for (int j = 0; j < 9; j++) mx = fmaxf(mx, lg[j]);
    float sum = 0.f;
#pragma unroll
    for (int j = 0; j < 9; j++) { lg[j] = expf(lg[j] - mx); sum += lg[j]; }
    float inv = 1.f / sum;
#pragma unroll
    for (int j = 0; j < 9; j++)
        if (lane == j) msoft[(size_t)z * 36864 + p * 9 + j] = lg[j] * inv;
}

__device__ __forceinline__ int cidx(int y, int x) {
    int yc = min(max(y, 0), 63), xc = min(max(x, 0), 63);
    return ((yc + 1) * 66 + (xc + 1)) * CDIM;
}
__device__ __forceinline__ float cval(int y, int x) {
    return (y >= 0 && y < 64 && x >= 0 && x < 64) ? 1.f : 0.f;
}

__global__ void k_offmask2(const float* __restrict__ offs, const float* __restrict__ msoft,
                           int4* __restrict__ idx4o, float4* __restrict__ w4o) {
    int id = blockIdx.x * 256 + threadIdx.x;
    int z = id / 36864, r = id % 36864, k = r >> 12, p = r & 4095;
    const float* ofz = offs + ((size_t)z * HW + p) * 18;
    float dy = ofz[2 * k], dx = ofz[2 * k + 1];
    float mk = msoft[(size_t)z * 36864 + k * 4096 + p];
    int h = p >> 6, w = p & 63;
    float py = (float)(h - 1 + k / 3) + dy;
    float px = (float)(w - 1 + k % 3) + dx;
    float y0f = floorf(py), x0f = floorf(px);
    int y0 = (int)y0f, x0 = (int)x0f;
    float wy1 = py - y0f, wx1 = px - x0f, wy0 = 1.f - wy1, wx0 = 1.f - wx1;
    idx4o[id] = make_int4(cidx(y0, x0), cidx(y0, x0 + 1), cidx(y0 + 1, x0), cidx(y0 + 1, x0 + 1));
    w4o[id] = make_float4(wy0 * wx0 * cval(y0, x0) * mk, wy0 * wx1 * cval(y0, x0 + 1) * mk,
                          wy1 * wx0 * cval(y0 + 1, x0) * mk, wy1 * wx1 * cval(y0 + 1, x0 + 1) * mk);
}

// ---------------------------------------------------------------- batchnorm
__global__ void k_bnstats(const u16* __restrict__ dout, float* __restrict__ mu,
                          float* __restrict__ rs) {
    int z = blockIdx.y;
    int c = blockIdx.x * 64 + threadIdx.x;
    int ty = threadIdx.y;
    const u16* d = dout + (size_t)z * HW * CDIM + c;
    float s1 = 0.f, s2 = 0.f;
    for (int p = ty; p < 4096; p += 8) {
        float v = bf2f(d[(size_t)p * CDIM]);
        s1 += v; s2 += v * v;
    }
    __shared__ float l1[8][64], l2[8][64];
    l1[ty][threadIdx.x] = s1; l2[ty][threadIdx.x] = s2;
    __syncthreads();
    if (ty == 0) {
        for (int y = 1; y < 8; y++) { s1 += l1[y][threadIdx.x]; s2 += l2[y][threadIdx.x]; }
        float m = s1 / 4096.f;
        float var = s2 / 4096.f - m * m;
        mu[z * 768 + c] = m;
        rs[z * 768 + c] = rsqrtf(var + 1e-5f);
    }
}

__global__ void k_bnapply(const u16* __restrict__ dout, const float* __restrict__ mu,
                          const float* __restrict__ rs, const float* __restrict__ g,
                          const float* __restrict__ b, u16* __restrict__ blk) {
    size_t i = ((size_t)blockIdx.x * 256 + threadIdx.x) * 8;
    int c = (int)(i % CDIM);
    int z = (int)(i / ((size_t)HW * CDIM));
    const float* muz = mu + z * 768;
    const float* rsz = rs + z * 768;
    uint4 in = *(const uint4*)(dout + i);
    const u16* u = (const u16*)&in;
    u16 o[8];
#pragma unroll
    for (int e = 0; e < 8; e++) {
        int ce = c + e;
        float v = (bf2f(u[e]) - muz[ce]) * rsz[ce] * g[ce] + b[ce];
        o[e] = f2bf(fmaxf(v, 0.f));
    }
    *(uint4*)(blk + i) = *(uint4*)o;
}

// ---------------------------------------------------------------- CAM
__global__ void k_q(const float* __restrict__ X, const float* __restrict__ chq,
                    float* __restrict__ q) {
    int wid = threadIdx.x >> 6, lane = threadIdx.x & 63;
    int p = blockIdx.x * 4 + wid;
    const float* xr = X + (size_t)p * CDIM;
    float s = 0.f;
#pragma unroll
    for (int j = 0; j < 12; j++) s += xr[lane + 64 * j] * chq[lane + 64 * j];
#pragma unroll
    for (int o = 32; o > 0; o >>= 1) s += __shfl_xor(s, o, 64);
    if (lane == 0) q[p] = s;
}

__global__ void k_soft4096(const float* __restrict__ q, float* __restrict__ sqn,
                           float* __restrict__ xq) {
    __shared__ float red[4];
    int tid = threadIdx.x, lane = tid & 63, wid = tid >> 6;
    float m = -1e30f;
    for (int i = tid; i < 4096; i += 256) m = fmaxf(m, q[i]);
    for (int o = 32; o > 0; o >>= 1) m = fmaxf(m, __shfl_xor(m, o, 64));
    if (lane == 0) red[wid] = m;
    __syncthreads();
    float bm = fmaxf(fmaxf(red[0], red[1]), fmaxf(red[2], red[3]));
    __syncthreads();
    float s = 0.f;
    for (int i = tid; i < 4096; i += 256) {
        float e = expf(q[i] - bm);
        sqn[i] = e; s += e;
    }
    for (int o = 32; o > 0; o >>= 1) s += __shfl_xor(s, o, 64);
    if (lane == 0) red[wid] = s;
    __syncthreads();
    float inv = 1.f / (red[0] + red[1] + red[2] + red[3]);
    for (int i = tid; i < 4096; i += 256) sqn[i] *= inv;
    for (int c = tid; c < 768; c += 256) xq[c] = 0.f;
}

__global__ void k_xq(const float* __restrict__ X, const float* __restrict__ sqn,
                     float* __restrict__ xq) {
    int p0 = blockIdx.x * 128;
    for (int c = threadIdx.x; c < 768; c += 256) {
        float a = 0.f;
        for (int p = p0; p < p0 + 128; p++) a += sqn[p] * X[(size_t)p * CDIM + c];
        atomicAdd(&xq[c], a);
    }
}

// wvq[o] = chv[o][:] . xq   (384 rows, wave per row)
__global__ void k_gemv384(const float* __restrict__ chv, const float* __restrict__ xq,
                          float* __restrict__ wvq) {
    int wid = threadIdx.x >> 6, lane = threadIdx.x & 63;
    int o = blockIdx.x * 4 + wid;
    const float* r = chv + (size_t)o * 768;
    float s = 0.f;
#pragma unroll
    for (int j = 0; j < 12; j++) s += r[lane + 64 * j] * xq[lane + 64 * j];
#pragma unroll
    for (int off = 32; off > 0; off >>= 1) s += __shfl_xor(s, off, 64);
    if (lane == 0) wvq[o] = s;
}

// wzv[c] = chz[c][:] . wvq   (768 rows, wave per row)
__global__ void k_gemv768(const float* __restrict__ chz, const float* __restrict__ wvq,
                          float* __restrict__ wzv) {
    int wid = threadIdx.x >> 6, lane = threadIdx.x & 63;
    int c = blockIdx.x * 4 + wid;
    const float* r = chz + (size_t)c * 384;
    float s = 0.f;
#pragma unroll
    for (int j = 0; j < 6; j++) s += r[lane + 64 * j] * wvq[lane + 64 * j];
#pragma unroll
    for (int off = 32; off > 0; off >>= 1) s += __shfl_xor(s, off, 64);
    if (lane == 0) wzv[c] = s;
}

// LN(768) + sigmoid -> sgate
__global__ void k_lngate(const float* __restrict__ wzv, const float* __restrict__ lng,
                         const float* __restrict__ lnb, float* __restrict__ sgate) {
    __shared__ float red[8];
    int tid = threadIdx.x, lane = tid & 63, wid = tid >> 6;
    float a = wzv[tid], b = wzv[tid + 256], c = wzv[tid + 512];
    float s1 = a + b + c, s2 = a * a + b * b + c * c;
    for (int o = 32; o > 0; o >>= 1) { s1 += __shfl_xor(s1, o, 64); s2 += __shfl_xor(s2, o, 64); }
    if (lane == 0) { red[wid] = s1; red[4 + wid] = s2; }
    __syncthreads();
    s1 = red[0] + red[1] + red[2] + red[3];
    s2 = red[4] + red[5] + red[6] + red[7];
    float mean = s1 / 768.f, var = s2 / 768.f - mean * mean, rstd = rsqrtf(var + 1e-5f);
    for (int cc = tid; cc < 768; cc += 256) {
        float tv = (wzv[cc] - mean) * rstd * lng[cc] + lnb[cc];
        sgate[cc] = 1.f / (1.f + expf(-tv));
    }
}

__global__ void k_xatt(const float* __restrict__ X, const float* __restrict__ sgate,
                       u16* __restrict__ xatt) {
    size_t i = ((size_t)blockIdx.x * 256 + threadIdx.x) * 4;
    int c = (int)(i % CDIM);
    float4 v = *(const float4*)(X + i);
    u16 o[4] = {f2bf(v.x * sgate[c]), f2bf(v.y * sgate[c + 1]),
                f2bf(v.z * sgate[c + 2]), f2bf(v.w * sgate[c + 3])};
    *(uint2*)(xatt + i) = *(uint2*)o;
}

// column max over P2[4096][384] — 24 blocks x 16 cols, coalesced
__global__ void k_colmax24(const float* __restrict__ P2, float* __restrict__ m2) {
    __shared__ float red[16][17];
    int col = blockIdx.x * 16 + threadIdx.x;
    float m = -1e30f;
    for (int p = threadIdx.y; p < 4096; p += 16) m = fmaxf(m, P2[(size_t)p * 384 + col]);
    red[threadIdx.y][threadIdx.x] = m;
    __syncthreads();
    if (threadIdx.y == 0) {
        for (int y = 1; y < 16; y++) m = fmaxf(m, red[y][threadIdx.x]);
        m2[col] = m;
    }
}

// softmax over 384 -> sq2
__global__ void k_sm384(const float* __restrict__ m2, float* __restrict__ sq2) {
    __shared__ float red[6];
    int tid = threadIdx.x, lane = tid & 63, wid = tid >> 6;
    float v = m2[tid];
    float m = v;
    for (int o = 32; o > 0; o >>= 1) m = fmaxf(m, __shfl_xor(m, o, 64));
    if (lane == 0) red[wid] = m;
    __syncthreads();
    m = red[0];
    for (int w = 1; w < 6; w++) m = fmaxf(m, red[w]);
    __syncthreads();
    float e = expf(v - m);
    float s = e;
    for (int o = 32; o > 0; o >>= 1) s += __shfl_xor(s, o, 64);
    if (lane == 0) red[wid] = s;
    __syncthreads();
    float tot = 0.f;
    for (int w = 0; w < 6; w++) tot += red[w];
    sq2[tid] = e / tot;
}

// sv[c] = sum_o sq2[o] * spv[o][c]  — 12 blocks x 64 cols, 4-way o-split
__global__ void k_sv(const float* __restrict__ sq2, const float* __restrict__ spv,
                     float* __restrict__ sv) {
    __shared__ float part[4][64];
    int c = blockIdx.x * 64 + (threadIdx.x & 63);
    int seg = threadIdx.x >> 6;
    float a = 0.f;
    for (int o = seg * 96; o < seg * 96 + 96; o++) a += sq2[o] * spv[(size_t)o * 768 + c];
    part[seg][threadIdx.x & 63] = a;
    __syncthreads();
    if (seg == 0) sv[c] = part[0][threadIdx.x] + part[1][threadIdx.x] +
                          part[2][threadIdx.x] + part[3][threadIdx.x];
}

__global__ void k_final(const float* __restrict__ X, const float* __restrict__ x5,
                        const float* __restrict__ sgate, const float* __restrict__ sv,
                        const float* __restrict__ ng, const float* __restrict__ nb,
                        float* __restrict__ out) {
    int wid = threadIdx.x >> 6, lane = threadIdx.x & 63;
    int p = blockIdx.x * 4 + wid;
    const float* xr = X + (size_t)p * CDIM;
    const float* x5r = x5 + (size_t)p * CDIM;
    float xa[12];
    float d = 0.f;
#pragma unroll
    for (int j = 0; j < 12; j++) {
        int c = lane + 64 * j;
        float a = xr[c] * sgate[c];
        xa[j] = a;
        d += sv[c] * a;
    }
#pragma unroll
    for (int o = 32; o > 0; o >>= 1) d += __shfl_xor(d, o, 64);
    float wz2 = 1.f / (1.f + expf(-d));
    float s1 = 0.f, s2 = 0.f;
#pragma unroll
    for (int j = 0; j < 12; j++) {
        int c = lane + 64 * j;
        float y = wz2 * xa[j] + xr[c] + x5r[c];
        xa[j] = y;
        s1 += y; s2 += y * y;
    }
#pragma unroll
    for (int o = 32; o > 0; o >>= 1) { s1 += __shfl_xor(s1, o, 64); s2 += __shfl_xor(s2, o, 64); }
    float mean = s1 / 768.f, var = s2 / 768.f - mean * mean, rstd = rsqrtf(var + 1e-5f);
#pragma unroll
    for (int j = 0; j < 12; j++) {
        int c = lane + 64 * j;
        out[(size_t)p * CDIM + c] = (xa[j] - mean) * rstd * ng[c] + nb[c];
    }
}

// ---------------------------------------------------------------- launch
extern "C" void kernel_launch(void* const* d_in, const int* in_sizes, int n_in,
                              void* d_out, int out_size, void* d_ws, size_t ws_size,
                              hipStream_t stream) {
    const float* xin[5];
    for (int i = 0; i < 5; i++) xin[i] = (const float*)d_in[i];
    const float* conv_w = (const float*)d_in[5];
    const float* conv_b = (const float*)d_in[6];
    const float* off_w = (const float*)d_in[7];
    const float* off_b = (const float*)d_in[8];
    const float* msk_w = (const float*)d_in[9];
    const float* msk_b = (const float*)d_in[10];
    const float* bn_g = (const float*)d_in[11];
    const float* bn_b = (const float*)d_in[12];
    const float* chq_w = (const float*)d_in[13];
    const float* chv_w = (const float*)d_in[14];
    const float* chz_w = (const float*)d_in[15];
    const float* ln_g = (const float*)d_in[16];
    const float* ln_b = (const float*)d_in[17];
    const float* spq_w = (const float*)d_in[18];
    const float* spv_w = (const float*)d_in[19];
    const float* wsrc[8];
    for (int i = 0; i < 8; i++) wsrc[i] = (const float*)d_in[20 + i];
    const float* norm_g = (const float*)d_in[28];
    const float* norm_b = (const float*)d_in[29];
    float* out = (float*)d_out;

    char* wsb = (char*)d_ws;
    size_t off = 0;
    auto take = [&](size_t n) -> char* {
        char* p = wsb + off;
        off = (off + n + 255) & ~(size_t)255;
        return p;
    };
    u16* xpad = (u16*)take(5ll * PPIX * CDIM * 2);
    u16* Wt = (u16*)take(9ll * CDIM * CDIM * 2);
    u16* omblk = (u16*)take(5ll * HW * CDIM * 2);
    float* offs = (float*)take(5ll * HW * 18 * 4);
    float* msoft = (float*)take(5ll * 36864 * 4);
    int4* idx4 = (int4*)take(5ll * 9 * 4096 * 16);
    float4* w4 = (float4*)take(5ll * 9 * 4096 * 16);
    u16* dout = (u16*)take(5ll * HW * CDIM * 2);
    u16* wb = (u16*)take(1790ll * 768 * 2);
    float* Xcat = (float*)take((size_t)HW * CDIM * 4);
    float* mu = (float*)take(5 * 768 * 4);
    float* rs = (float*)take(5 * 768 * 4);
    float* qv = (float*)take(4096 * 4);
    float* sqn = (float*)take(4096 * 4);
    float* xq = (float*)take(768 * 4);
    float* wvq = (float*)take(384 * 4);
    float* wzv = (float*)take(768 * 4);
    float* sgate = (float*)take(768 * 4);
    float* m2 = (float*)take(384 * 4);
    float* sq2 = (float*)take(384 * 4);
    float* sv = (float*)take(768 * 4);
    u16* xatt = dout;
    float* P2 = (float*)((char*)dout + 8388608);
    u16* blk = omblk;
    (void)ws_size; (void)in_sizes; (void)n_in; (void)out_size;

    int rows[9] = {30, 100, 150, 150, 220, 220, 268, 268, 384};
    int roff[9]; int acc = 0;
    for (int i = 0; i < 9; i++) { roff[i] = acc; acc += rows[i]; }
    u16* spqb = wb + (size_t)roff[8] * 768;

    WbP wp;
    for (int i = 0; i < 8; i++) { wp.src[i] = wsrc[i]; wp.dst[i] = wb + (size_t)roff[i] * 768; wp.n[i] = rows[i] * 768; }
    wp.src[8] = spq_w; wp.dst[8] = spqb; wp.n[8] = rows[8] * 768;

    ProjP pp;
    pp.b1[0] = wb + (size_t)roff[0] * 768; pp.b2[0] = nullptr;
    pp.b1[1] = wb + (size_t)roff[1] * 768; pp.b2[1] = nullptr;
    pp.b1[2] = wb + (size_t)roff[2] * 768; pp.b2[2] = wb + (size_t)roff[3] * 768;
    pp.b1[3] = wb + (size_t)roff[4] * 768; pp.b2[3] = wb + (size_t)roff[5] * 768;
    pp.b1[4] = wb + (size_t)roff[6] * 768; pp.b2[4] = wb + (size_t)roff[7] * 768;
    int chs[5] = {30, 100, 150, 220, 268};
    int cof[5] = {0, 30, 130, 280, 500};
    for (int i = 0; i < 5; i++) { pp.ch[i] = chs[i]; pp.choff[i] = cof[i]; }
    ProjP pdum = {};

    Ptr5 xs;
    for (int i = 0; i < 5; i++) xs.p[i] = xin[i];

    // ---- prep ----
    k_prep_xpad<<<dim3(PPIX, 5), 192, 0, stream>>>(xs, xpad);
    k_prep_wt<<<dim3(768), 256, 0, stream>>>(conv_w, Wt);
    k_prep_wb<<<dim3(288, 9), 256, 0, stream>>>(wp);

    // ---- heavy path ----
    k_gemm128<G_CONV><<<dim3(32, 6, 5), 256, 0, stream>>>(xpad, nullptr, Wt, conv_b,
                                                          omblk, nullptr, pdum);
    k_offmask1<<<dim3(1024, 5), 256, 0, stream>>>(omblk, off_w, off_b, msk_w, msk_b, offs, msoft);
    k_offmask2<<<dim3(720), 256, 0, stream>>>(offs, msoft, idx4, w4);
    k_gdef<<<dim3(32, 3, 5), 256, 0, stream>>>(xpad, Wt, idx4, w4, conv_b, dout);
    k_bnstats<<<dim3(12, 5), dim3(64, 8), 0, stream>>>(dout, mu, rs);
    k_bnapply<<<dim3(7680), 256, 0, stream>>>(dout, mu, rs, bn_g, bn_b, blk);
    k_gemm128<G_PROJ><<<dim3(32, 3, 5), 256, 0, stream>>>(xpad, blk, nullptr, nullptr,
                                                          nullptr, Xcat, pp);

    // ---- CAM ----
    k_q<<<dim3(1024), 256, 0, stream>>>(Xcat, chq_w, qv);
    k_soft4096<<<dim3(1), 256, 0, stream>>>(qv, sqn, xq);
    k_xq<<<dim3(32), 256, 0, stream>>>(Xcat, sqn, xq);
    k_gemv384<<<dim3(96), 256, 0, stream>>>(chv_w, xq, wvq);
    k_gemv768<<<dim3(192), 256, 0, stream>>>(chz_w, wvq, wzv);
    k_lngate<<<dim3(1), 256, 0, stream>>>(wzv, ln_g, ln_b, sgate);
    k_xatt<<<dim3(3072), 256, 0, stream>>>(Xcat, sgate, xatt);
    k_gemm128<G_SPAT><<<dim3(32, 3, 1), 256, 0, stream>>>(xpad, xatt, spqb, nullptr,
                                                          nullptr, P2, pdum);
    k_colmax24<<<dim3(24), dim3(16, 16), 0, stream>>>(P2, m2);
    k_sm384<<<dim3(1), 384, 0, stream>>>(m2, sq2);
    k_sv<<<dim3(12), 256, 0, stream>>>(sq2, spv_w, sv);

    // ---- residual + final LayerNorm ----
    k_final<<<dim3(1024), 256, 0, stream>>>(Xcat, xin[4], sgate, sv, norm_g, norm_b, out);
}